// Round 1
// 1039.896 us; speedup vs baseline: 1.0224x; 1.0224x over previous
//
#include <hip/hip_runtime.h>

typedef __bf16 v8bf __attribute__((ext_vector_type(8)));
typedef __bf16 v4bf __attribute__((ext_vector_type(4)));
typedef float  v4f  __attribute__((ext_vector_type(4)));

// ---- problem constants (from reference) ----
static constexpr int cN0 = 400000, cN1 = 200000, cN2 = 100000, cN3 = 50000;
static constexpr int cE0 = 3200000, cE1 = 1600000, cE2 = 800000;
static constexpr int F_IN = 128, F_HID = 256;
static constexpr int CAP = 64;   // slots per target; deg~Binom(E,1/n)=16 mean, P(>=64)~1e-19

// mega1 role block counts (all exact multiples of 256 where noted)
static constexpr int NB_C0 = (cE0 + 255) / 256;          // 12500
static constexpr int NB_C1 = (cE1 + 255) / 256;          // 6250
static constexpr int NB_C2 = (cE2 + 255) / 256;          // 3125
static constexpr int NB_XC = (cN0 * F_IN / 4) / 256;     // 50000 (exact)
static constexpr int NB_W0 = (F_IN * F_HID) / 256;       // 128 (exact)
static constexpr int NB_W1 = (F_HID * F_HID) / 256;      // 256 (exact)
static constexpr int NB_TOTAL = NB_C0 + NB_C1 + NB_C2 + NB_XC + NB_W0 + 2 * NB_W1;

// ---------------- mega kernel 1: all independent pre-work ----------------
// Roles (in dispatch order, longest pole first):
//   count+slot-scatter L0/L1/L2: per edge one returning atomicAdd to pk
//     (low16 = full degree, high16 = contributing count = slot index),
//     row written into padded slot array when row < n_dst.
//   xconv: fp32 x -> bf16 xb (gather working set 205->102 MB)
//   wconv x3: fp32 W[K,N] -> bf16 Wt[N,K]
// Atomic-bound count blocks leave HBM idle -> streaming roles ride along free.
__launch_bounds__(256)
__global__ void mega1_kernel(const int* __restrict__ ei0, const int* __restrict__ ei1,
                             const int* __restrict__ ei2,
                             int* __restrict__ pk0, int* __restrict__ pk1,
                             int* __restrict__ pk2,
                             int* __restrict__ slots0, int* __restrict__ slots1,
                             int* __restrict__ slots2,
                             const float* __restrict__ x, __bf16* __restrict__ xb,
                             const float* __restrict__ W0, const float* __restrict__ W1,
                             const float* __restrict__ W2,
                             __bf16* __restrict__ w0t, __bf16* __restrict__ w1t,
                             __bf16* __restrict__ w2t) {
    int b = blockIdx.x;
    int tid = threadIdx.x;

    if (b < NB_C0) {
        int e = b * 256 + tid;
        if (e < cE0) {
            int r = ei0[e], c = ei0[cE0 + e];
            bool ct = r < cN1;
            int old = atomicAdd(&pk0[c], ct ? (1 | (1 << 16)) : 1);
            int s = old >> 16;
            if (ct && s < CAP) slots0[(size_t)c * CAP + s] = r;
        }
        return;
    }
    b -= NB_C0;
    if (b < NB_C1) {
        int e = b * 256 + tid;
        if (e < cE1) {
            int r = ei1[e], c = ei1[cE1 + e];
            bool ct = r < cN2;
            int old = atomicAdd(&pk1[c], ct ? (1 | (1 << 16)) : 1);
            int s = old >> 16;
            if (ct && s < CAP) slots1[(size_t)c * CAP + s] = r;
        }
        return;
    }
    b -= NB_C1;
    if (b < NB_C2) {
        int e = b * 256 + tid;
        if (e < cE2) {
            int r = ei2[e], c = ei2[cE2 + e];
            bool ct = r < cN3;
            int old = atomicAdd(&pk2[c], ct ? (1 | (1 << 16)) : 1);
            int s = old >> 16;
            if (ct && s < CAP) slots2[(size_t)c * CAP + s] = r;
        }
        return;
    }
    b -= NB_C2;
    if (b < NB_XC) {
        int i = b * 256 + tid;           // exact: no bound check needed
        v4f v = *(const v4f*)(x + (size_t)i * 4);
        v4bf r;
        r.x = (__bf16)v.x; r.y = (__bf16)v.y; r.z = (__bf16)v.z; r.w = (__bf16)v.w;
        *(v4bf*)(xb + (size_t)i * 4) = r;
        return;
    }
    b -= NB_XC;
    if (b < NB_W0) {                     // W0: [128,256] -> [256,128]
        int i = b * 256 + tid;
        int k = i >> 8, n = i & 255;
        w0t[(size_t)n * F_IN + k] = (__bf16)W0[i];
        return;
    }
    b -= NB_W0;
    if (b < NB_W1) {                     // W1: [256,256] -> [256,256]
        int i = b * 256 + tid;
        int k = i >> 8, n = i & 255;
        w1t[(size_t)n * F_HID + k] = (__bf16)W1[i];
        return;
    }
    b -= NB_W1;
    {                                    // W2: [256,256] -> [256,256]
        int i = b * 256 + tid;
        int k = i >> 8, n = i & 255;
        w2t[(size_t)n * F_HID + k] = (__bf16)W2[i];
    }
}

// ---------------- hdr pass: atomic-free (replaces offsets_kernel) ----------------
// Unified over all 3 layers: [0,cN1)=L0 fill2, [cN1,cN1+cN2)=L1 fill2, rest L2 fill1.
// hdr[c] = {cnt, bits(selfw), bits(dis_c), 0}; dis[c] for agg's per-edge coef.
__global__ void hdr_kernel(const int* __restrict__ pk, int4* __restrict__ hdr,
                           float* __restrict__ dis) {
    int i = blockIdx.x * blockDim.x + threadIdx.x;
    constexpr int total = cN1 + cN2 + cN3;
    if (i >= total) return;
    float fill = (i < cN1 + cN2) ? 2.0f : 1.0f;
    int p = pk[i];
    int deg = p & 0xffff, cnt = p >> 16;
    float d = rsqrtf((float)deg + fill);  // deg+fill >= 1 always for targets
    dis[i] = d;
    float selfw = fill * d * d;
    hdr[i] = make_int4(cnt, __builtin_bit_cast(int, selfw),
                       __builtin_bit_cast(int, d), 0);
}

// ---------------- aggregation: one 16/32-lane GROUP per target ----------------
// agg[c] = selfw*src[c] + sum_e dis[row_e]*dis_c * src[row_e]
// Rows come from the padded slot array (CAP per target). coef computed inline:
// dis[row] is a random 4B load from an 800KB L2/L3-resident table, issued in
// parallel with the 256-512B feature row fetch -> hidden. Unroll-2 with
// prefetch of the next pair of slot entries while current rows are in flight.
template<int F>
__launch_bounds__(256)
__global__ void agg_kernel(const __bf16* __restrict__ src, const int4* __restrict__ hdr,
                           const int* __restrict__ slots, const float* __restrict__ dis,
                           int n_dst, __bf16* __restrict__ out) {
    constexpr int T = F / 8;            // lanes per target row (16 B each): 16 or 32
    constexpr int TPB = 256 / T;        // targets per block: 16 or 8
    int tid = threadIdx.x;
    int grp = tid / T;
    int t   = tid % T;
    int c = blockIdx.x * TPB + grp;
    if (c >= n_dst) return;

    int4 h = hdr[c];                    // broadcast within group
    int n = h.x;
    if (n > CAP) n = CAP;               // unreachable (P~1e-19), safety only
    float selfw = __builtin_bit_cast(float, h.y);
    float dc    = __builtin_bit_cast(float, h.z);

    v8bf sv = *(const v8bf*)(src + (size_t)c * F + t * 8);
    float acc[8];
#pragma unroll
    for (int j = 0; j < 8; j++) acc[j] = selfw * (float)sv[j];

    const int* sp = slots + (size_t)c * CAP;
    int ra, rb;
    if (n > 0) ra = sp[0];
    if (n > 1) rb = sp[1];
    int i = 0;
    for (; i + 2 <= n; i += 2) {
        float ca = dis[ra] * dc;
        float cb = dis[rb] * dc;
        v8bf wa = *(const v8bf*)(src + (size_t)(unsigned)(ra * F) + t * 8);
        v8bf wb = *(const v8bf*)(src + (size_t)(unsigned)(rb * F) + t * 8);
        if (i + 2 < n) ra = sp[i + 2];  // prefetch while rows are in flight
        if (i + 3 < n) rb = sp[i + 3];
#pragma unroll
        for (int j = 0; j < 8; j++) acc[j] += ca * (float)wa[j];
#pragma unroll
        for (int j = 0; j < 8; j++) acc[j] += cb * (float)wb[j];
    }
    if (i < n) {
        float ca = dis[ra] * dc;
        v8bf wa = *(const v8bf*)(src + (size_t)(unsigned)(ra * F) + t * 8);
#pragma unroll
        for (int j = 0; j < 8; j++) acc[j] += ca * (float)wa[j];
    }

    v8bf res;
#pragma unroll
    for (int j = 0; j < 8; j++) res[j] = (__bf16)acc[j];
    *(v8bf*)(out + (size_t)c * F + t * 8) = res;
}

// ---------------- GEMM: C[M,N] = A[M,K] @ B[K,N] + bias (opt ReLU) ----------------
// A bf16 row-major [M,K]; Bt bf16 = B transposed, row-major [N,K]. 64x64 tile,
// 4 waves each 32x32 via mfma_f32_16x16x32_bf16.
// Verified gfx950 layouts: A-frag lane l: A[m=l&15][k=(l>>4)*8+j];
// B-frag lane l: B[k=(l>>4)*8+j][n=l&15] = Bt[n][k]; D lane l reg r: C[(l>>4)*4+r][l&15].
template<int K, bool RELU, typename OutT>
__launch_bounds__(256)
__global__ void gemm_bias_kernel(const __bf16* __restrict__ A, const __bf16* __restrict__ Bt,
                                 const float* __restrict__ bias, OutT* __restrict__ C,
                                 int M, int N) {
    constexpr int LDA = 40;  // 32 + 8 halves pad: row stride 80B (16B-aligned, bank-spread)
    __shared__ __align__(16) __bf16 la[64 * LDA];
    __shared__ __align__(16) __bf16 lb[64 * LDA];
    int tid  = threadIdx.x;
    int wave = tid >> 6, lane = tid & 63;
    int quad = lane >> 4, l15 = lane & 15;
    int wm = (wave >> 1) * 32, wn = (wave & 1) * 32;
    int tm = blockIdx.x * 64, tn = blockIdx.y * 64;

    v4f acc[2][2] = {};

    int srow = tid >> 2;               // 0..63
    int sseg = (tid & 3) * 8;          // halves within 32-wide k block
    long arow = tm + srow;
    if (arow >= M) arow = M - 1;       // clamp: garbage rows only affect unstored outputs
    const __bf16* ag = A  + (size_t)arow * K + sseg;
    const __bf16* bg = Bt + (size_t)(tn + srow) * K + sseg;  // N divisible by 64

    for (int k0 = 0; k0 < K; k0 += 32) {
        __syncthreads();
        uint4 av = *(const uint4*)(ag + k0);
        uint4 bv = *(const uint4*)(bg + k0);
        *(uint4*)&la[srow * LDA + sseg] = av;
        *(uint4*)&lb[srow * LDA + sseg] = bv;
        __syncthreads();

        v8bf af0 = *(const v8bf*)&la[(wm +      l15) * LDA + quad * 8];
        v8bf af1 = *(const v8bf*)&la[(wm + 16 + l15) * LDA + quad * 8];
        v8bf bf0 = *(const v8bf*)&lb[(wn +      l15) * LDA + quad * 8];
        v8bf bf1 = *(const v8bf*)&lb[(wn + 16 + l15) * LDA + quad * 8];

        acc[0][0] = __builtin_amdgcn_mfma_f32_16x16x32_bf16(af0, bf0, acc[0][0], 0, 0, 0);
        acc[0][1] = __builtin_amdgcn_mfma_f32_16x16x32_bf16(af0, bf1, acc[0][1], 0, 0, 0);
        acc[1][0] = __builtin_amdgcn_mfma_f32_16x16x32_bf16(af1, bf0, acc[1][0], 0, 0, 0);
        acc[1][1] = __builtin_amdgcn_mfma_f32_16x16x32_bf16(af1, bf1, acc[1][1], 0, 0, 0);
    }

#pragma unroll
    for (int mi = 0; mi < 2; mi++) {
#pragma unroll
        for (int r = 0; r < 4; r++) {
            int row = tm + wm + mi * 16 + quad * 4 + r;
            if (row < M) {
#pragma unroll
                for (int ni = 0; ni < 2; ni++) {
                    int col = tn + wn + ni * 16 + l15;
                    float v = acc[mi][ni][r] + bias[col];
                    if (RELU) v = fmaxf(v, 0.0f);
                    C[(size_t)row * N + col] = (OutT)v;
                }
            }
        }
    }
}

// ---------------- host ----------------
static inline size_t align256(size_t x) { return (x + 255) & ~(size_t)255; }

extern "C" void kernel_launch(void* const* d_in, const int* in_sizes, int n_in,
                              void* d_out, int out_size, void* d_ws, size_t ws_size,
                              hipStream_t stream) {
    const float* x   = (const float*)d_in[0];
    const int*   ei0 = (const int*)d_in[1];
    const int*   ei1 = (const int*)d_in[2];
    const int*   ei2 = (const int*)d_in[3];
    const float* W0  = (const float*)d_in[4];
    const float* b0  = (const float*)d_in[5];
    const float* W1  = (const float*)d_in[6];
    const float* b1  = (const float*)d_in[7];
    const float* W2  = (const float*)d_in[8];
    const float* b2  = (const float*)d_in[9];
    float* out = (float*)d_out;

    constexpr int totalT = cN1 + cN2 + cN3;   // 350000

    // ---- workspace carve-up (re-poisoned each call; we init what we read) ----
    char* ws = (char*)d_ws;
    size_t o = 0;
    auto alloc = [&](size_t bytes) { void* p = ws + o; o += align256(bytes); return p; };
    int*    pk     = (int*)   alloc((size_t)totalT * 4);       // pk0|pk1|pk2 contiguous
    int4*   hdr    = (int4*)  alloc((size_t)totalT * 16);      // {cnt, selfw, dis_c, 0}
    float*  dis    = (float*) alloc((size_t)totalT * 4);
    __bf16* w0t    = (__bf16*)alloc((size_t)F_IN * F_HID * 2);
    __bf16* w1t    = (__bf16*)alloc((size_t)F_HID * F_HID * 2);
    __bf16* w2t    = (__bf16*)alloc((size_t)F_HID * F_HID * 2);
    int*    slots1 = (int*)   alloc((size_t)cN2 * CAP * 4);    // 25.6 MB
    __bf16* aggb   = (__bf16*)alloc((size_t)cN1 * F_IN * 2);   // 51.2 MB (max agg size)
    __bf16* h1     = (__bf16*)alloc((size_t)cN1 * F_HID * 2);  // 102.4 MB
    __bf16* xb     = (__bf16*)alloc((size_t)cN0 * F_IN * 2);   // 102.4 MB
    // lifetime unions (all hand-verified against the serial dispatch order):
    //   slots0 (51.2 MB) lives in h1: dead after agg0; gemm0 then overwrites h1.
    //   slots2 (12.8 MB) lives in d_out: dead after agg2; gemm2 overwrites out fully.
    //   h2 (51.2 MB) lives in xb: xb dead after agg0; h2 first written at gemm1.
    int*    slots0 = (int*)h1;
    int*    slots2 = (int*)d_out;
    __bf16* h2     = xb;
    int* pk0 = pk, *pk1 = pk + cN1, *pk2 = pk + cN1 + cN2;
    (void)ws_size; (void)n_in; (void)in_sizes; (void)out_size;

    // ---- phase 0: zero all counters in one memset ----
    hipMemsetAsync(pk, 0, (size_t)totalT * 4, stream);

    // ---- phase 1: all independent pre-work fused (counts+slots x3, xconv, wconv x3) ----
    mega1_kernel<<<NB_TOTAL, 256, 0, stream>>>(ei0, ei1, ei2, pk0, pk1, pk2,
                                               slots0, slots1, slots2,
                                               x, xb, W0, W1, W2, w0t, w1t, w2t);

    // ---- phase 2: atomic-free hdr/dis for all 3 layers ----
    hdr_kernel<<<(totalT + 255) / 256, 256, 0, stream>>>(pk, hdr, dis);

    // ---- layer 0: x[400000,128] -> h1[200000,256], fill=2, ReLU ----
    agg_kernel<F_IN><<<(cN1 + 15) / 16, 256, 0, stream>>>(xb, hdr, slots0, dis, cN1, aggb);
    gemm_bias_kernel<F_IN, true, __bf16><<<dim3((cN1 + 63) / 64, F_HID / 64), 256, 0, stream>>>(
        aggb, w0t, b0, h1, cN1, F_HID);

    // ---- layer 1: h1[200000,256] -> h2[100000,256], fill=2, ReLU ----
    agg_kernel<F_HID><<<(cN2 + 7) / 8, 256, 0, stream>>>(h1, hdr + cN1, slots1, dis + cN1,
                                                         cN2, aggb);
    gemm_bias_kernel<F_HID, true, __bf16><<<dim3((cN2 + 63) / 64, F_HID / 64), 256, 0, stream>>>(
        aggb, w1t, b1, h2, cN2, F_HID);

    // ---- layer 2: h2[100000,256] -> out[50000,256], fill=1, no ReLU, fp32 out ----
    agg_kernel<F_HID><<<(cN3 + 7) / 8, 256, 0, stream>>>(h2, hdr + cN1 + cN2, slots2,
                                                         dis + cN1 + cN2, cN3, aggb);
    gemm_bias_kernel<F_HID, false, float><<<dim3((cN3 + 63) / 64, F_HID / 64), 256, 0, stream>>>(
        aggb, w2t, b2, out, cN3, F_HID);
}

// Round 2
// 1003.265 us; speedup vs baseline: 1.0597x; 1.0365x over previous
//
#include <hip/hip_runtime.h>

typedef __bf16 v8bf __attribute__((ext_vector_type(8)));
typedef __bf16 v4bf __attribute__((ext_vector_type(4)));
typedef float  v4f  __attribute__((ext_vector_type(4)));

// ---- problem constants (from reference) ----
static constexpr int cN0 = 400000, cN1 = 200000, cN2 = 100000, cN3 = 50000;
static constexpr int cE0 = 3200000, cE1 = 1600000, cE2 = 800000;
static constexpr int F_IN = 128, F_HID = 256;
static constexpr int CAP = 64;   // slots per target; deg~Binom(E,1/n)=16 mean, P(>=64)~1e-19

// role block counts (all E and sizes are exact multiples of 256)
static constexpr int NB_C0 = cE0 / 256;                  // 12500
static constexpr int NB_C1 = cE1 / 256;                  // 6250
static constexpr int NB_C2 = cE2 / 256;                  // 3125
static constexpr int NB_XC = (cN0 * F_IN / 4) / 256;     // 50000
static constexpr int NB_W0 = (F_IN * F_HID) / 256;       // 128
static constexpr int NB_W1 = (F_HID * F_HID) / 256;      // 256
static constexpr int NB_K1 = NB_C0 + NB_XC + NB_W0 + 2 * NB_W1;

static constexpr int NB_AGG0 = cN1 / 16;                 // 12500 (F=128 -> 16 targets/block)
static constexpr int GX0 = cN1 / 64;                     // 3125
static constexpr int NB_G0 = GX0 * (F_HID / 64);         // 12500

// ---------------- CSR count+slot role (one returning atomic per edge) ----------------
// pk[c]: low16 = full degree (all edges, reference semantics), high16 = contributing
// count = slot index. Contributing edges (row < n_dst) write row into padded slots.
__device__ __forceinline__ void csr_edge_role(const int* __restrict__ ei, int E,
                                              int n_dst, int* __restrict__ pk,
                                              int* __restrict__ slots, int b) {
    int e = b * 256 + threadIdx.x;
    if (e >= E) return;
    int r = ei[e], c = ei[E + e];
    bool ct = r < n_dst;
    int old = atomicAdd(&pk[c], ct ? (1 | (1 << 16)) : 1);
    int s = old >> 16;
    if (ct && s < CAP) slots[(size_t)c * CAP + s] = r;
}

// ---------------- aggregation body: one 16/32-lane GROUP per target ----------------
// agg[c] = selfw*src[c] + sum_e dis[row_e]*dis_c * src[row_e]
// dis recomputed inline from pk (4B L2-resident load + rsqrt, VALU is idle):
// bit-identical to the old hdr/dis path, which this replaces entirely.
template<int F>
__device__ __forceinline__ void agg_body(const __bf16* __restrict__ src,
                                         const int* __restrict__ pk,
                                         const int* __restrict__ slots,
                                         int n_dst, float fill,
                                         __bf16* __restrict__ out, int blk) {
    constexpr int T = F / 8;            // lanes per target row (16 B each): 16 or 32
    constexpr int TPB = 256 / T;        // targets per block: 16 or 8
    int tid = threadIdx.x;
    int grp = tid / T;
    int t   = tid % T;
    int c = blk * TPB + grp;
    if (c >= n_dst) return;

    int p = pk[c];                      // broadcast within group
    int n = p >> 16;
    if (n > CAP) n = CAP;               // unreachable (P~1e-19), safety only
    float dc = rsqrtf((float)(p & 0xffff) + fill);   // deg+fill >= 1 for targets
    float selfw = fill * dc * dc;

    v8bf sv = *(const v8bf*)(src + (size_t)c * F + t * 8);
    float acc[8];
#pragma unroll
    for (int j = 0; j < 8; j++) acc[j] = selfw * (float)sv[j];

    const int* sp = slots + (size_t)c * CAP;
    int ra, rb;
    if (n > 0) ra = sp[0];
    if (n > 1) rb = sp[1];
    int i = 0;
    for (; i + 2 <= n; i += 2) {
        int pa = pk[ra], pb = pk[rb];   // L2-resident 4B, issued alongside row fetch
        v8bf wa = *(const v8bf*)(src + (size_t)(unsigned)(ra * F) + t * 8);
        v8bf wb = *(const v8bf*)(src + (size_t)(unsigned)(rb * F) + t * 8);
        if (i + 2 < n) ra = sp[i + 2];  // prefetch while rows are in flight
        if (i + 3 < n) rb = sp[i + 3];
        float ca = rsqrtf((float)(pa & 0xffff) + fill) * dc;
        float cb = rsqrtf((float)(pb & 0xffff) + fill) * dc;
#pragma unroll
        for (int j = 0; j < 8; j++) acc[j] += ca * (float)wa[j];
#pragma unroll
        for (int j = 0; j < 8; j++) acc[j] += cb * (float)wb[j];
    }
    if (i < n) {
        int pa = pk[ra];
        v8bf wa = *(const v8bf*)(src + (size_t)(unsigned)(ra * F) + t * 8);
        float ca = rsqrtf((float)(pa & 0xffff) + fill) * dc;
#pragma unroll
        for (int j = 0; j < 8; j++) acc[j] += ca * (float)wa[j];
    }

    v8bf res;
#pragma unroll
    for (int j = 0; j < 8; j++) res[j] = (__bf16)acc[j];
    *(v8bf*)(out + (size_t)c * F + t * 8) = res;
}

// ---------------- K1: CSR0 + xconv + wconv x3 (independent pre-work) ----------------
__launch_bounds__(256)
__global__ void k1_kernel(const int* __restrict__ ei0, int* __restrict__ pk0,
                          int* __restrict__ slots0,
                          const float* __restrict__ x, __bf16* __restrict__ xb,
                          const float* __restrict__ W0, const float* __restrict__ W1,
                          const float* __restrict__ W2,
                          __bf16* __restrict__ w0t, __bf16* __restrict__ w1t,
                          __bf16* __restrict__ w2t) {
    int b = blockIdx.x;
    int tid = threadIdx.x;
    if (b < NB_C0) { csr_edge_role(ei0, cE0, cN1, pk0, slots0, b); return; }
    b -= NB_C0;
    if (b < NB_XC) {                    // xconv: fp32 -> bf16 (exact blocks)
        int i = b * 256 + tid;
        v4f v = *(const v4f*)(x + (size_t)i * 4);
        v4bf r;
        r.x = (__bf16)v.x; r.y = (__bf16)v.y; r.z = (__bf16)v.z; r.w = (__bf16)v.w;
        *(v4bf*)(xb + (size_t)i * 4) = r;
        return;
    }
    b -= NB_XC;
    if (b < NB_W0) {                    // W0: [128,256] -> [256,128]
        int i = b * 256 + tid;
        int k = i >> 8, n = i & 255;
        w0t[(size_t)n * F_IN + k] = (__bf16)W0[i];
        return;
    }
    b -= NB_W0;
    if (b < NB_W1) {                    // W1: [256,256] -> [256,256]
        int i = b * 256 + tid;
        int k = i >> 8, n = i & 255;
        w1t[(size_t)n * F_HID + k] = (__bf16)W1[i];
        return;
    }
    b -= NB_W1;
    {                                   // W2: [256,256] -> [256,256]
        int i = b * 256 + tid;
        int k = i >> 8, n = i & 255;
        w2t[(size_t)n * F_HID + k] = (__bf16)W2[i];
    }
}

// ---------------- K2: agg layer0 (BW-bound) overlapped with CSR1 (atomic-bound) ------
__launch_bounds__(256)
__global__ void k2_kernel(const __bf16* __restrict__ xb, const int* __restrict__ pk0,
                          const int* __restrict__ slots0, __bf16* __restrict__ aggb,
                          const int* __restrict__ ei1, int* __restrict__ pk1,
                          int* __restrict__ slots1) {
    int b = blockIdx.x;
    if (b < NB_C1) { csr_edge_role(ei1, cE1, cN2, pk1, slots1, b); return; }
    agg_body<F_IN>(xb, pk0, slots0, cN1, 2.0f, aggb, b - NB_C1);
}

// ---------------- K3: gemm layer0 (MFMA-bound) overlapped with CSR2 ----------------
// GEMM: C[M,N] = A[M,K] @ B[K,N] + bias, ReLU, bf16 out. M=cN1, N=F_HID, K=F_IN.
// Verified gfx950 layouts: A-frag lane l: A[m=l&15][k=(l>>4)*8+j];
// B-frag lane l: B[k=(l>>4)*8+j][n=l&15] = Bt[n][k]; D lane l reg r: C[(l>>4)*4+r][l&15].
__launch_bounds__(256)
__global__ void k3_kernel(const __bf16* __restrict__ A, const __bf16* __restrict__ Bt,
                          const float* __restrict__ bias, __bf16* __restrict__ C,
                          const int* __restrict__ ei2, int* __restrict__ pk2,
                          int* __restrict__ slots2) {
    constexpr int K = F_IN, M = cN1, N = F_HID;
    constexpr int LDA = 40;  // 32 + 8 halves pad: row stride 80B (16B-aligned, bank-spread)
    __shared__ __align__(16) __bf16 la[64 * LDA];
    __shared__ __align__(16) __bf16 lb[64 * LDA];
    int b = blockIdx.x;
    if (b < NB_C2) { csr_edge_role(ei2, cE2, cN3, pk2, slots2, b); return; }
    b -= NB_C2;
    int bx = b % GX0, by = b / GX0;

    int tid  = threadIdx.x;
    int wave = tid >> 6, lane = tid & 63;
    int quad = lane >> 4, l15 = lane & 15;
    int wm = (wave >> 1) * 32, wn = (wave & 1) * 32;
    int tm = bx * 64, tn = by * 64;

    v4f acc[2][2] = {};

    int srow = tid >> 2;
    int sseg = (tid & 3) * 8;
    const __bf16* ag = A  + (size_t)(tm + srow) * K + sseg;   // M divisible by 64
    const __bf16* bg = Bt + (size_t)(tn + srow) * K + sseg;   // N divisible by 64

    for (int k0 = 0; k0 < K; k0 += 32) {
        __syncthreads();
        uint4 av = *(const uint4*)(ag + k0);
        uint4 bv = *(const uint4*)(bg + k0);
        *(uint4*)&la[srow * LDA + sseg] = av;
        *(uint4*)&lb[srow * LDA + sseg] = bv;
        __syncthreads();

        v8bf af0 = *(const v8bf*)&la[(wm +      l15) * LDA + quad * 8];
        v8bf af1 = *(const v8bf*)&la[(wm + 16 + l15) * LDA + quad * 8];
        v8bf bf0 = *(const v8bf*)&lb[(wn +      l15) * LDA + quad * 8];
        v8bf bf1 = *(const v8bf*)&lb[(wn + 16 + l15) * LDA + quad * 8];

        acc[0][0] = __builtin_amdgcn_mfma_f32_16x16x32_bf16(af0, bf0, acc[0][0], 0, 0, 0);
        acc[0][1] = __builtin_amdgcn_mfma_f32_16x16x32_bf16(af0, bf1, acc[0][1], 0, 0, 0);
        acc[1][0] = __builtin_amdgcn_mfma_f32_16x16x32_bf16(af1, bf0, acc[1][0], 0, 0, 0);
        acc[1][1] = __builtin_amdgcn_mfma_f32_16x16x32_bf16(af1, bf1, acc[1][1], 0, 0, 0);
    }

#pragma unroll
    for (int mi = 0; mi < 2; mi++) {
#pragma unroll
        for (int r = 0; r < 4; r++) {
            int row = tm + wm + mi * 16 + quad * 4 + r;
#pragma unroll
            for (int ni = 0; ni < 2; ni++) {
                int col = tn + wn + ni * 16 + l15;
                float v = acc[mi][ni][r] + bias[col];
                v = fmaxf(v, 0.0f);
                C[(size_t)row * N + col] = (__bf16)v;
            }
        }
    }
}

// ---------------- standalone agg (layers 1,2) ----------------
template<int F>
__launch_bounds__(256)
__global__ void agg_kernel(const __bf16* __restrict__ src, const int* __restrict__ pk,
                           const int* __restrict__ slots, int n_dst, float fill,
                           __bf16* __restrict__ out) {
    agg_body<F>(src, pk, slots, n_dst, fill, out, blockIdx.x);
}

// ---------------- standalone GEMM (layers 1,2) ----------------
template<int K, bool RELU, typename OutT>
__launch_bounds__(256)
__global__ void gemm_bias_kernel(const __bf16* __restrict__ A, const __bf16* __restrict__ Bt,
                                 const float* __restrict__ bias, OutT* __restrict__ C,
                                 int M, int N) {
    constexpr int LDA = 40;
    __shared__ __align__(16) __bf16 la[64 * LDA];
    __shared__ __align__(16) __bf16 lb[64 * LDA];
    int tid  = threadIdx.x;
    int wave = tid >> 6, lane = tid & 63;
    int quad = lane >> 4, l15 = lane & 15;
    int wm = (wave >> 1) * 32, wn = (wave & 1) * 32;
    int tm = blockIdx.x * 64, tn = blockIdx.y * 64;

    v4f acc[2][2] = {};

    int srow = tid >> 2;
    int sseg = (tid & 3) * 8;
    long arow = tm + srow;
    if (arow >= M) arow = M - 1;       // clamp: garbage rows only affect unstored outputs
    const __bf16* ag = A  + (size_t)arow * K + sseg;
    const __bf16* bg = Bt + (size_t)(tn + srow) * K + sseg;  // N divisible by 64

    for (int k0 = 0; k0 < K; k0 += 32) {
        __syncthreads();
        uint4 av = *(const uint4*)(ag + k0);
        uint4 bv = *(const uint4*)(bg + k0);
        *(uint4*)&la[srow * LDA + sseg] = av;
        *(uint4*)&lb[srow * LDA + sseg] = bv;
        __syncthreads();

        v8bf af0 = *(const v8bf*)&la[(wm +      l15) * LDA + quad * 8];
        v8bf af1 = *(const v8bf*)&la[(wm + 16 + l15) * LDA + quad * 8];
        v8bf bf0 = *(const v8bf*)&lb[(wn +      l15) * LDA + quad * 8];
        v8bf bf1 = *(const v8bf*)&lb[(wn + 16 + l15) * LDA + quad * 8];

        acc[0][0] = __builtin_amdgcn_mfma_f32_16x16x32_bf16(af0, bf0, acc[0][0], 0, 0, 0);
        acc[0][1] = __builtin_amdgcn_mfma_f32_16x16x32_bf16(af0, bf1, acc[0][1], 0, 0, 0);
        acc[1][0] = __builtin_amdgcn_mfma_f32_16x16x32_bf16(af1, bf0, acc[1][0], 0, 0, 0);
        acc[1][1] = __builtin_amdgcn_mfma_f32_16x16x32_bf16(af1, bf1, acc[1][1], 0, 0, 0);
    }

#pragma unroll
    for (int mi = 0; mi < 2; mi++) {
#pragma unroll
        for (int r = 0; r < 4; r++) {
            int row = tm + wm + mi * 16 + quad * 4 + r;
            if (row < M) {
#pragma unroll
                for (int ni = 0; ni < 2; ni++) {
                    int col = tn + wn + ni * 16 + l15;
                    float v = acc[mi][ni][r] + bias[col];
                    if (RELU) v = fmaxf(v, 0.0f);
                    C[(size_t)row * N + col] = (OutT)v;
                }
            }
        }
    }
}

// ---------------- host ----------------
static inline size_t align256(size_t x) { return (x + 255) & ~(size_t)255; }

extern "C" void kernel_launch(void* const* d_in, const int* in_sizes, int n_in,
                              void* d_out, int out_size, void* d_ws, size_t ws_size,
                              hipStream_t stream) {
    const float* x   = (const float*)d_in[0];
    const int*   ei0 = (const int*)d_in[1];
    const int*   ei1 = (const int*)d_in[2];
    const int*   ei2 = (const int*)d_in[3];
    const float* W0  = (const float*)d_in[4];
    const float* b0  = (const float*)d_in[5];
    const float* W1  = (const float*)d_in[6];
    const float* b1  = (const float*)d_in[7];
    const float* W2  = (const float*)d_in[8];
    const float* b2  = (const float*)d_in[9];
    float* out = (float*)d_out;

    constexpr int totalT = cN1 + cN2 + cN3;   // 350000

    // ---- workspace carve-up (re-poisoned each call; we init what we read) ----
    char* ws = (char*)d_ws;
    size_t o = 0;
    auto alloc = [&](size_t bytes) { void* p = ws + o; o += align256(bytes); return p; };
    int*    pk     = (int*)   alloc((size_t)totalT * 4);       // pk0|pk1|pk2 contiguous
    __bf16* w0t    = (__bf16*)alloc((size_t)F_IN * F_HID * 2);
    __bf16* w1t    = (__bf16*)alloc((size_t)F_HID * F_HID * 2);
    __bf16* w2t    = (__bf16*)alloc((size_t)F_HID * F_HID * 2);
    int*    slots1 = (int*)   alloc((size_t)cN2 * CAP * 4);    // 25.6 MB
    __bf16* aggb   = (__bf16*)alloc((size_t)cN1 * F_IN * 2);   // 51.2 MB (max agg size)
    __bf16* h1     = (__bf16*)alloc((size_t)cN1 * F_HID * 2);  // 102.4 MB
    __bf16* xb     = (__bf16*)alloc((size_t)cN0 * F_IN * 2);   // 102.4 MB
    // lifetime unions (hand-verified against the serial dispatch order):
    //   slots0 (51.2 MB) in h1: written K1, read K2(agg0); K3(gemm0) then writes h1.
    //   slots2 (12.8 MB) in d_out: written K3, read agg2; gemm2 overwrites out fully.
    //   h2 (51.2 MB) in xb: xb last read K2(agg0); h2 first written at gemm1.
    int*    slots0 = (int*)h1;
    int*    slots2 = (int*)d_out;
    __bf16* h2     = xb;
    int* pk0 = pk, *pk1 = pk + cN1, *pk2 = pk + cN1 + cN2;
    (void)ws_size; (void)n_in; (void)in_sizes; (void)out_size;

    // ---- zero all three pk segments in one memset ----
    hipMemsetAsync(pk, 0, (size_t)totalT * 4, stream);

    // ---- K1: CSR0 + xconv + wconv x3 ----
    k1_kernel<<<NB_K1, 256, 0, stream>>>(ei0, pk0, slots0, x, xb, W0, W1, W2,
                                         w0t, w1t, w2t);

    // ---- K2: agg layer0 || CSR1 ----
    k2_kernel<<<NB_C1 + NB_AGG0, 256, 0, stream>>>(xb, pk0, slots0, aggb,
                                                   ei1, pk1, slots1);

    // ---- K3: gemm layer0 (ReLU, bf16 out) || CSR2 ----
    k3_kernel<<<NB_C2 + NB_G0, 256, 0, stream>>>(aggb, w0t, b0, h1, ei2, pk2, slots2);

    // ---- layer 1: h1[200000,256] -> h2[100000,256], fill=2, ReLU ----
    agg_kernel<F_HID><<<cN2 / 8, 256, 0, stream>>>(h1, pk1, slots1, cN2, 2.0f, aggb);
    gemm_bias_kernel<F_HID, true, __bf16><<<dim3((cN2 + 63) / 64, F_HID / 64), 256, 0, stream>>>(
        aggb, w1t, b1, h2, cN2, F_HID);

    // ---- layer 2: h2[100000,256] -> out[50000,256], fill=1, no ReLU, fp32 out ----
    agg_kernel<F_HID><<<cN3 / 8, 256, 0, stream>>>(h2, pk2, slots2, cN3, 1.0f, aggb);
    gemm_bias_kernel<F_HID, false, float><<<dim3((cN3 + 63) / 64, F_HID / 64), 256, 0, stream>>>(
        aggb, w2t, b2, out, cN3, F_HID);
}

// Round 3
// 769.644 us; speedup vs baseline: 1.3814x; 1.3035x over previous
//
#include <hip/hip_runtime.h>

typedef __bf16 v8bf __attribute__((ext_vector_type(8)));
typedef __bf16 v4bf __attribute__((ext_vector_type(4)));
typedef float  v4f  __attribute__((ext_vector_type(4)));

// ---- problem constants (from reference) ----
static constexpr int cN0 = 400000, cN1 = 200000, cN2 = 100000, cN3 = 50000;
static constexpr int cE0 = 3200000, cE1 = 1600000, cE2 = 800000;
static constexpr int F_IN = 128, F_HID = 256;
static constexpr int CAP = 64;   // slots per target; deg~Binom(E,1/n)=16 mean, P(>=64)~1e-19

// role block counts (all exact)
static constexpr int NB_C0 = cE0 / 256;                  // 12500
static constexpr int NB_C1 = cE1 / 256;                  // 6250
static constexpr int NB_C2 = cE2 / 256;                  // 3125
static constexpr int NB_XC = (cN0 * F_IN / 4) / 256;     // 50000 = 4 * NB_C0
static constexpr int NB_W0 = (F_IN * F_HID) / 256;       // 128
static constexpr int NB_W1 = (F_HID * F_HID) / 256;      // 256
static constexpr int MIX1  = NB_C0 + NB_XC;              // 62500, interleave 1:4
static constexpr int NB_K1 = MIX1 + NB_W0 + 2 * NB_W1;

static constexpr int NB_AGG0 = cN1 / 16;                 // 12500 = 2 * NB_C1
static constexpr int NB_K2   = NB_C1 + NB_AGG0;          // interleave 1:2
static constexpr int GX0   = cN1 / 64;                   // 3125
static constexpr int NB_G0 = GX0 * (F_HID / 64);         // 12500 = 4 * NB_C2
static constexpr int NB_K3 = NB_C2 + NB_G0;              // interleave 1:4

// ---------------- CSR count+slot role (one returning atomic per edge) ----------------
// pk[c]: low16 = full degree (all edges, reference semantics), high16 = contributing
// count = slot index. Contributing edges (row < n_dst) write row into padded slots.
__device__ __forceinline__ void csr_edge_role(const int* __restrict__ ei, int E,
                                              int n_dst, int* __restrict__ pk,
                                              int* __restrict__ slots, int b) {
    int e = b * 256 + threadIdx.x;
    if (e >= E) return;
    int r = ei[e], c = ei[E + e];
    bool ct = r < n_dst;
    int old = atomicAdd(&pk[c], ct ? (1 | (1 << 16)) : 1);
    int s = old >> 16;
    if (ct && s < CAP) slots[(size_t)c * CAP + s] = r;
}

// ---------------- aggregation body: one 16/32-lane GROUP per target ----------------
// agg[c] = selfw*src[c] + sum_e dis[row_e]*dis_c * src[row_e]
// dis recomputed inline from pk (4B L2-resident load + rsqrt, VALU is idle):
// bit-identical to the reference normalization.
template<int F>
__device__ __forceinline__ void agg_body(const __bf16* __restrict__ src,
                                         const int* __restrict__ pk,
                                         const int* __restrict__ slots,
                                         int n_dst, float fill,
                                         __bf16* __restrict__ out, int blk) {
    constexpr int T = F / 8;            // lanes per target row (16 B each): 16 or 32
    constexpr int TPB = 256 / T;        // targets per block: 16 or 8
    int tid = threadIdx.x;
    int grp = tid / T;
    int t   = tid % T;
    int c = blk * TPB + grp;
    if (c >= n_dst) return;

    int p = pk[c];                      // broadcast within group
    int n = p >> 16;
    if (n > CAP) n = CAP;               // unreachable (P~1e-19), safety only
    float dc = rsqrtf((float)(p & 0xffff) + fill);   // deg+fill >= 1 for targets
    float selfw = fill * dc * dc;

    v8bf sv = *(const v8bf*)(src + (size_t)c * F + t * 8);
    float acc[8];
#pragma unroll
    for (int j = 0; j < 8; j++) acc[j] = selfw * (float)sv[j];

    const int* sp = slots + (size_t)c * CAP;
    int ra, rb;
    if (n > 0) ra = sp[0];
    if (n > 1) rb = sp[1];
    int i = 0;
    for (; i + 2 <= n; i += 2) {
        int pa = pk[ra], pb = pk[rb];   // L2-resident 4B, issued alongside row fetch
        v8bf wa = *(const v8bf*)(src + (size_t)(unsigned)(ra * F) + t * 8);
        v8bf wb = *(const v8bf*)(src + (size_t)(unsigned)(rb * F) + t * 8);
        if (i + 2 < n) ra = sp[i + 2];  // prefetch while rows are in flight
        if (i + 3 < n) rb = sp[i + 3];
        float ca = rsqrtf((float)(pa & 0xffff) + fill) * dc;
        float cb = rsqrtf((float)(pb & 0xffff) + fill) * dc;
#pragma unroll
        for (int j = 0; j < 8; j++) acc[j] += ca * (float)wa[j];
#pragma unroll
        for (int j = 0; j < 8; j++) acc[j] += cb * (float)wb[j];
    }
    if (i < n) {
        int pa = pk[ra];
        v8bf wa = *(const v8bf*)(src + (size_t)(unsigned)(ra * F) + t * 8);
        float ca = rsqrtf((float)(pa & 0xffff) + fill) * dc;
#pragma unroll
        for (int j = 0; j < 8; j++) acc[j] += ca * (float)wa[j];
    }

    v8bf res;
#pragma unroll
    for (int j = 0; j < 8; j++) res[j] = (__bf16)acc[j];
    *(v8bf*)(out + (size_t)c * F + t * 8) = res;
}

// ---------------- K1: CSR0 interleaved 1:4 with xconv; wconv in tail ----------------
// Interleave by blockIdx%5 so atomic-bound CSR blocks and streaming xconv blocks are
// co-resident on every CU from t=0 (contiguous role ranges dispatch serially).
__launch_bounds__(256)
__global__ void k1_kernel(const int* __restrict__ ei0, int* __restrict__ pk0,
                          int* __restrict__ slots0,
                          const float* __restrict__ x, __bf16* __restrict__ xb,
                          const float* __restrict__ W0, const float* __restrict__ W1,
                          const float* __restrict__ W2,
                          __bf16* __restrict__ w0t, __bf16* __restrict__ w1t,
                          __bf16* __restrict__ w2t) {
    int b = blockIdx.x;
    int tid = threadIdx.x;
    if (b < MIX1) {
        int q = b / 5, r = b % 5;
        if (r == 0) { csr_edge_role(ei0, cE0, cN1, pk0, slots0, q); return; }
        int i = (q * 4 + (r - 1)) * 256 + tid;   // xconv: fp32 -> bf16 (exact blocks)
        v4f v = *(const v4f*)(x + (size_t)i * 4);
        v4bf rv;
        rv.x = (__bf16)v.x; rv.y = (__bf16)v.y; rv.z = (__bf16)v.z; rv.w = (__bf16)v.w;
        *(v4bf*)(xb + (size_t)i * 4) = rv;
        return;
    }
    b -= MIX1;
    if (b < NB_W0) {                    // W0: [128,256] -> [256,128]
        int i = b * 256 + tid;
        int k = i >> 8, n = i & 255;
        w0t[(size_t)n * F_IN + k] = (__bf16)W0[i];
        return;
    }
    b -= NB_W0;
    if (b < NB_W1) {                    // W1: [256,256] -> [256,256]
        int i = b * 256 + tid;
        int k = i >> 8, n = i & 255;
        w1t[(size_t)n * F_HID + k] = (__bf16)W1[i];
        return;
    }
    b -= NB_W1;
    {                                   // W2: [256,256] -> [256,256]
        int i = b * 256 + tid;
        int k = i >> 8, n = i & 255;
        w2t[(size_t)n * F_HID + k] = (__bf16)W2[i];
    }
}

// ---------------- K2: agg layer0 interleaved 1:2 with CSR1 ----------------
__launch_bounds__(256)
__global__ void k2_kernel(const __bf16* __restrict__ xb, const int* __restrict__ pk0,
                          const int* __restrict__ slots0, __bf16* __restrict__ aggb,
                          const int* __restrict__ ei1, int* __restrict__ pk1,
                          int* __restrict__ slots1) {
    int b = blockIdx.x;
    int q = b / 3, r = b % 3;
    if (r == 0) { csr_edge_role(ei1, cE1, cN2, pk1, slots1, q); return; }
    agg_body<F_IN>(xb, pk0, slots0, cN1, 2.0f, aggb, q * 2 + (r - 1));
}

// ---------------- K3: gemm layer0 interleaved 1:4 with CSR2 ----------------
// GEMM: C[M,N] = A[M,K] @ B[K,N] + bias, ReLU, bf16 out. M=cN1, N=F_HID, K=F_IN.
// Verified gfx950 layouts: A-frag lane l: A[m=l&15][k=(l>>4)*8+j];
// B-frag lane l: B[k=(l>>4)*8+j][n=l&15] = Bt[n][k]; D lane l reg r: C[(l>>4)*4+r][l&15].
__launch_bounds__(256)
__global__ void k3_kernel(const __bf16* __restrict__ A, const __bf16* __restrict__ Bt,
                          const float* __restrict__ bias, __bf16* __restrict__ C,
                          const int* __restrict__ ei2, int* __restrict__ pk2,
                          int* __restrict__ slots2) {
    constexpr int K = F_IN, N = F_HID;
    constexpr int LDA = 40;  // 32 + 8 halves pad: row stride 80B (16B-aligned, bank-spread)
    __shared__ __align__(16) __bf16 la[64 * LDA];
    __shared__ __align__(16) __bf16 lb[64 * LDA];
    int b = blockIdx.x;
    int q = b / 5, r = b % 5;
    if (r == 0) { csr_edge_role(ei2, cE2, cN3, pk2, slots2, q); return; }
    int g = q * 4 + (r - 1);
    int bx = g % GX0, by = g / GX0;

    int tid  = threadIdx.x;
    int wave = tid >> 6, lane = tid & 63;
    int quad = lane >> 4, l15 = lane & 15;
    int wm = (wave >> 1) * 32, wn = (wave & 1) * 32;
    int tm = bx * 64, tn = by * 64;

    v4f acc[2][2] = {};

    int srow = tid >> 2;
    int sseg = (tid & 3) * 8;
    const __bf16* ag = A  + (size_t)(tm + srow) * K + sseg;   // M divisible by 64
    const __bf16* bg = Bt + (size_t)(tn + srow) * K + sseg;   // N divisible by 64

    for (int k0 = 0; k0 < K; k0 += 32) {
        __syncthreads();
        uint4 av = *(const uint4*)(ag + k0);
        uint4 bv = *(const uint4*)(bg + k0);
        *(uint4*)&la[srow * LDA + sseg] = av;
        *(uint4*)&lb[srow * LDA + sseg] = bv;
        __syncthreads();

        v8bf af0 = *(const v8bf*)&la[(wm +      l15) * LDA + quad * 8];
        v8bf af1 = *(const v8bf*)&la[(wm + 16 + l15) * LDA + quad * 8];
        v8bf bf0 = *(const v8bf*)&lb[(wn +      l15) * LDA + quad * 8];
        v8bf bf1 = *(const v8bf*)&lb[(wn + 16 + l15) * LDA + quad * 8];

        acc[0][0] = __builtin_amdgcn_mfma_f32_16x16x32_bf16(af0, bf0, acc[0][0], 0, 0, 0);
        acc[0][1] = __builtin_amdgcn_mfma_f32_16x16x32_bf16(af0, bf1, acc[0][1], 0, 0, 0);
        acc[1][0] = __builtin_amdgcn_mfma_f32_16x16x32_bf16(af1, bf0, acc[1][0], 0, 0, 0);
        acc[1][1] = __builtin_amdgcn_mfma_f32_16x16x32_bf16(af1, bf1, acc[1][1], 0, 0, 0);
    }

#pragma unroll
    for (int mi = 0; mi < 2; mi++) {
#pragma unroll
        for (int rr = 0; rr < 4; rr++) {
            int row = tm + wm + mi * 16 + quad * 4 + rr;
#pragma unroll
            for (int ni = 0; ni < 2; ni++) {
                int col = tn + wn + ni * 16 + l15;
                float v = acc[mi][ni][rr] + bias[col];
                v = fmaxf(v, 0.0f);
                C[(size_t)row * N + col] = (__bf16)v;
            }
        }
    }
}

// ---------------- standalone agg (layers 1,2) ----------------
template<int F>
__launch_bounds__(256)
__global__ void agg_kernel(const __bf16* __restrict__ src, const int* __restrict__ pk,
                           const int* __restrict__ slots, int n_dst, float fill,
                           __bf16* __restrict__ out) {
    agg_body<F>(src, pk, slots, n_dst, fill, out, blockIdx.x);
}

// ---------------- standalone GEMM (layers 1,2) ----------------
template<int K, bool RELU, typename OutT>
__launch_bounds__(256)
__global__ void gemm_bias_kernel(const __bf16* __restrict__ A, const __bf16* __restrict__ Bt,
                                 const float* __restrict__ bias, OutT* __restrict__ C,
                                 int M, int N) {
    constexpr int LDA = 40;
    __shared__ __align__(16) __bf16 la[64 * LDA];
    __shared__ __align__(16) __bf16 lb[64 * LDA];
    int tid  = threadIdx.x;
    int wave = tid >> 6, lane = tid & 63;
    int quad = lane >> 4, l15 = lane & 15;
    int wm = (wave >> 1) * 32, wn = (wave & 1) * 32;
    int tm = blockIdx.x * 64, tn = blockIdx.y * 64;

    v4f acc[2][2] = {};

    int srow = tid >> 2;
    int sseg = (tid & 3) * 8;
    long arow = tm + srow;
    if (arow >= M) arow = M - 1;       // clamp: garbage rows only affect unstored outputs
    const __bf16* ag = A  + (size_t)arow * K + sseg;
    const __bf16* bg = Bt + (size_t)(tn + srow) * K + sseg;  // N divisible by 64

    for (int k0 = 0; k0 < K; k0 += 32) {
        __syncthreads();
        uint4 av = *(const uint4*)(ag + k0);
        uint4 bv = *(const uint4*)(bg + k0);
        *(uint4*)&la[srow * LDA + sseg] = av;
        *(uint4*)&lb[srow * LDA + sseg] = bv;
        __syncthreads();

        v8bf af0 = *(const v8bf*)&la[(wm +      l15) * LDA + quad * 8];
        v8bf af1 = *(const v8bf*)&la[(wm + 16 + l15) * LDA + quad * 8];
        v8bf bf0 = *(const v8bf*)&lb[(wn +      l15) * LDA + quad * 8];
        v8bf bf1 = *(const v8bf*)&lb[(wn + 16 + l15) * LDA + quad * 8];

        acc[0][0] = __builtin_amdgcn_mfma_f32_16x16x32_bf16(af0, bf0, acc[0][0], 0, 0, 0);
        acc[0][1] = __builtin_amdgcn_mfma_f32_16x16x32_bf16(af0, bf1, acc[0][1], 0, 0, 0);
        acc[1][0] = __builtin_amdgcn_mfma_f32_16x16x32_bf16(af1, bf0, acc[1][0], 0, 0, 0);
        acc[1][1] = __builtin_amdgcn_mfma_f32_16x16x32_bf16(af1, bf1, acc[1][1], 0, 0, 0);
    }

#pragma unroll
    for (int mi = 0; mi < 2; mi++) {
#pragma unroll
        for (int r = 0; r < 4; r++) {
            int row = tm + wm + mi * 16 + quad * 4 + r;
            if (row < M) {
#pragma unroll
                for (int ni = 0; ni < 2; ni++) {
                    int col = tn + wn + ni * 16 + l15;
                    float v = acc[mi][ni][r] + bias[col];
                    if (RELU) v = fmaxf(v, 0.0f);
                    C[(size_t)row * N + col] = (OutT)v;
                }
            }
        }
    }
}

// ---------------- host ----------------
static inline size_t align256(size_t x) { return (x + 255) & ~(size_t)255; }

extern "C" void kernel_launch(void* const* d_in, const int* in_sizes, int n_in,
                              void* d_out, int out_size, void* d_ws, size_t ws_size,
                              hipStream_t stream) {
    const float* x   = (const float*)d_in[0];
    const int*   ei0 = (const int*)d_in[1];
    const int*   ei1 = (const int*)d_in[2];
    const int*   ei2 = (const int*)d_in[3];
    const float* W0  = (const float*)d_in[4];
    const float* b0  = (const float*)d_in[5];
    const float* W1  = (const float*)d_in[6];
    const float* b1  = (const float*)d_in[7];
    const float* W2  = (const float*)d_in[8];
    const float* b2  = (const float*)d_in[9];
    float* out = (float*)d_out;

    constexpr int totalT = cN1 + cN2 + cN3;   // 350000

    // ---- workspace carve-up (re-poisoned each call; we init what we read) ----
    char* ws = (char*)d_ws;
    size_t o = 0;
    auto alloc = [&](size_t bytes) { void* p = ws + o; o += align256(bytes); return p; };
    int*    pk     = (int*)   alloc((size_t)totalT * 4);       // pk0|pk1|pk2 contiguous
    __bf16* w0t    = (__bf16*)alloc((size_t)F_IN * F_HID * 2);
    __bf16* w1t    = (__bf16*)alloc((size_t)F_HID * F_HID * 2);
    __bf16* w2t    = (__bf16*)alloc((size_t)F_HID * F_HID * 2);
    int*    slots1 = (int*)   alloc((size_t)cN2 * CAP * 4);    // 25.6 MB
    __bf16* aggb   = (__bf16*)alloc((size_t)cN1 * F_IN * 2);   // 51.2 MB (max agg size)
    __bf16* h1     = (__bf16*)alloc((size_t)cN1 * F_HID * 2);  // 102.4 MB
    __bf16* xb     = (__bf16*)alloc((size_t)cN0 * F_IN * 2);   // 102.4 MB
    // lifetime unions (hand-verified against the serial dispatch order):
    //   slots0 (51.2 MB) in h1: written K1, read K2(agg0); K3(gemm0) then writes h1.
    //   slots2 (12.8 MB) in d_out: written K3, read agg2; gemm2 overwrites out fully.
    //   h2 (51.2 MB) in xb: xb last read K2(agg0); h2 first written at gemm1.
    int*    slots0 = (int*)h1;
    int*    slots2 = (int*)d_out;
    __bf16* h2     = xb;
    int* pk0 = pk, *pk1 = pk + cN1, *pk2 = pk + cN1 + cN2;
    (void)ws_size; (void)n_in; (void)in_sizes; (void)out_size;

    // ---- zero all three pk segments in one memset ----
    hipMemsetAsync(pk, 0, (size_t)totalT * 4, stream);

    // ---- K1: CSR0 (1:4 interleaved with xconv) + wconv x3 ----
    k1_kernel<<<NB_K1, 256, 0, stream>>>(ei0, pk0, slots0, x, xb, W0, W1, W2,
                                         w0t, w1t, w2t);

    // ---- K2: agg layer0 || CSR1 (1:2 interleave) ----
    k2_kernel<<<NB_K2, 256, 0, stream>>>(xb, pk0, slots0, aggb, ei1, pk1, slots1);

    // ---- K3: gemm layer0 (ReLU, bf16 out) || CSR2 (1:4 interleave) ----
    k3_kernel<<<NB_K3, 256, 0, stream>>>(aggb, w0t, b0, h1, ei2, pk2, slots2);

    // ---- layer 1: h1[200000,256] -> h2[100000,256], fill=2, ReLU ----
    agg_kernel<F_HID><<<cN2 / 8, 256, 0, stream>>>(h1, pk1, slots1, cN2, 2.0f, aggb);
    gemm_bias_kernel<F_HID, true, __bf16><<<dim3((cN2 + 63) / 64, F_HID / 64), 256, 0, stream>>>(
        aggb, w1t, b1, h2, cN2, F_HID);

    // ---- layer 2: h2[100000,256] -> out[50000,256], fill=1, no ReLU, fp32 out ----
    agg_kernel<F_HID><<<cN3 / 8, 256, 0, stream>>>(h2, pk2, slots2, cN3, 1.0f, aggb);
    gemm_bias_kernel<F_HID, false, float><<<dim3((cN3 + 63) / 64, F_HID / 64), 256, 0, stream>>>(
        aggb, w2t, b2, out, cN3, F_HID);
}